// Round 8
// baseline (323.528 us; speedup 1.0000x reference)
//
#include <hip/hip_runtime.h>

// LIF spiking neuron, T=4, TAU=1.0, THRESH=1.0, hard reset.
// x: [T*B, C, H, W] fp32 viewed as [T, S]; per element:
//   mem += x_t; spike = (mem >= 1) ? 1 : 0; mem = spike ? 0 : mem;
// Streaming roofline: 205.5 MB in + 205.5 MB out -> ~65 us @ 6.3 TB/s.
//
// R7 -> R8: ILP test. Each thread now owns TWO float4 columns (h=0,1 at
// t and t+NT), 8 independent nt-loads in flight, half the waves. Both
// load instructions stay unit-stride across lanes (columns are separate
// contiguous ranges -- avoids the per-thread-32B stride-32 trap).
// H1 (BW-bound already): null -> residual is harness overhead.
// H2 (MLP-bound): -10..-30 us.

#define T_STEPS 4

typedef float f4 __attribute__((ext_vector_type(4)));

__global__ __launch_bounds__(256) void lif_kernel(
    const f4* __restrict__ x, f4* __restrict__ out, int s4, int nt) {
    const int t = blockIdx.x * 256 + threadIdx.x;  // t < nt = s4/2

    // 8 independent coalesced 16B non-temporal loads, all issued up front
    f4 a0 = __builtin_nontemporal_load(&x[t]);
    f4 a1 = __builtin_nontemporal_load(&x[t + s4]);
    f4 a2 = __builtin_nontemporal_load(&x[t + 2 * s4]);
    f4 a3 = __builtin_nontemporal_load(&x[t + 3 * s4]);
    f4 b0 = __builtin_nontemporal_load(&x[t + nt]);
    f4 b1 = __builtin_nontemporal_load(&x[t + nt + s4]);
    f4 b2 = __builtin_nontemporal_load(&x[t + nt + 2 * s4]);
    f4 b3 = __builtin_nontemporal_load(&x[t + nt + 3 * s4]);

    f4 memA = {0.f, 0.f, 0.f, 0.f};
    f4 memB = {0.f, 0.f, 0.f, 0.f};
    f4 sp;

#define STEP(MEM, XT, OUTIDX)                                   \
    MEM.x += (XT).x; MEM.y += (XT).y;                           \
    MEM.z += (XT).z; MEM.w += (XT).w;                           \
    sp.x = (MEM.x >= 1.0f) ? 1.0f : 0.0f;                       \
    sp.y = (MEM.y >= 1.0f) ? 1.0f : 0.0f;                       \
    sp.z = (MEM.z >= 1.0f) ? 1.0f : 0.0f;                       \
    sp.w = (MEM.w >= 1.0f) ? 1.0f : 0.0f;                       \
    MEM.x = (sp.x != 0.0f) ? 0.0f : MEM.x;                      \
    MEM.y = (sp.y != 0.0f) ? 0.0f : MEM.y;                      \
    MEM.z = (sp.z != 0.0f) ? 0.0f : MEM.z;                      \
    MEM.w = (sp.w != 0.0f) ? 0.0f : MEM.w;                      \
    __builtin_nontemporal_store(sp, &out[OUTIDX]);

    STEP(memA, a0, t)
    STEP(memA, a1, t + s4)
    STEP(memA, a2, t + 2 * s4)
    STEP(memA, a3, t + 3 * s4)
    STEP(memB, b0, t + nt)
    STEP(memB, b1, t + nt + s4)
    STEP(memB, b2, t + nt + 2 * s4)
    STEP(memB, b3, t + nt + 3 * s4)
#undef STEP
}

extern "C" void kernel_launch(void* const* d_in, const int* in_sizes, int n_in,
                              void* d_out, int out_size, void* d_ws, size_t ws_size,
                              hipStream_t stream) {
    const float* x = (const float*)d_in[0];
    float* out = (float*)d_out;

    const int total = in_sizes[0];          // 51,380,224
    const int slice = total / T_STEPS;      // 12,845,056 floats per time slice
    const int s4 = slice / 4;               // 3,211,264 float4 per time slice
    const int nt = s4 / 2;                  // 1,605,632 threads, 2 columns each

    const int block = 256;
    const int grid = nt / block;            // 6,272 -- exact, no remainder

    lif_kernel<<<grid, block, 0, stream>>>(
        (const f4*)x, (f4*)out, s4, nt);
}